// Round 12
// baseline (327.416 us; speedup 1.0000x reference)
//
#include <hip/hip_runtime.h>
#include <hip/hip_cooperative_groups.h>
#include <stdint.h>

namespace cg = cooperative_groups;

#define B 4
#define N 16384
#define S 2048
#define C 64
#define K 64
#define OC 66
#define R2 0.01f
#define NXCD 8
#define TP 1089   // per-wave gather staging: 64 points x pitch 17 (+skew)

typedef float f32x4 __attribute__((ext_vector_type(4)));

// ---------------------------------------------------------------------------
// Cooperative fused kernel. 2048 blocks x 256 threads (8 blocks/CU, all
// co-resident). Per block:
//   phase A: ball-query scan (4 waves = 4 queries) + ch0/1 stores
//            + one 64n x 32c transpose slice feat->ft (spread in time, so
//            slices overlap other blocks' straggler scans)
//   grid.sync()
//   phase B: gather from ft + LDS-staged 256B stores (R9 structure verbatim)
// ---------------------------------------------------------------------------
__global__ __launch_bounds__(256, 8)
void coop_kernel(const float* __restrict__ f,
                 const float* __restrict__ xyz,
                 const float* __restrict__ new_xyz,
                 const int* __restrict__ pointsnum,
                 float* __restrict__ ft,
                 float* __restrict__ out) {
    __shared__ float smem[4 * TP];         // union: transpose tile / staging
    __shared__ int   s_idx[4][K];

    const int t    = threadIdx.x;
    const int lane = t & 63;
    const int wu   = __builtin_amdgcn_readfirstlane(t >> 6);

    // bijective XCD swizzle for the query mapping (nwg = 2048, % 8 == 0)
    const int nwg = (B * S) / 4;
    const int bid = blockIdx.x;
    const int swz = (bid & (NXCD - 1)) * (nwg / NXCD) + (bid >> 3);

    const int q0 = swz * 4;
    const int b  = q0 >> 11;
    const int q  = q0 + wu;
    const int s  = (q0 & (S - 1)) + wu;

    const float qx = new_xyz[(size_t)q * 2 + 0];
    const float qy = new_xyz[(size_t)q * 2 + 1];
    const float* __restrict__ xb = xyz + (size_t)b * N * 2;

    // ---- Phase A1: ordered ball-query scan (R9 verbatim) ----
    int pn = pointsnum[b];
    pn = pn < 0 ? 0 : (pn > N ? N : pn);
    int cnt = 0;
    float2 p[4], pf[4];
    #pragma unroll
    for (int u = 0; u < 4; ++u) {
        const int i  = u * 64 + lane;
        const int ic = i < N ? i : N - 1;
        p[u] = *(const float2*)&xb[(size_t)ic * 2];
    }
    for (int base = 0; base < pn && cnt < K; base += 256) {
        #pragma unroll
        for (int u = 0; u < 4; ++u) {       // prefetch next super-chunk
            const int i  = base + 256 + u * 64 + lane;
            const int ic = i < N ? i : N - 1;
            pf[u] = *(const float2*)&xb[(size_t)ic * 2];
        }
        #pragma unroll
        for (int u = 0; u < 4; ++u) {
            const int i = base + u * 64 + lane;
            bool ok = false;
            if (i < pn) {
                // match numpy f32 rounding exactly: no FMA contraction
                const float dx = __fsub_rn(qx, p[u].x);
                const float dy = __fsub_rn(qy, p[u].y);
                const float d2 = __fadd_rn(__fmul_rn(dx, dx), __fmul_rn(dy, dy));
                ok = d2 < R2;
            }
            const unsigned long long m = __ballot(ok);
            if (ok) {
                const int pos = cnt + __popcll(m & ((1ull << lane) - 1ull));
                if (pos < K) s_idx[wu][pos] = i;
            }
            cnt += __popcll(m);
        }
        #pragma unroll
        for (int u = 0; u < 4; ++u) p[u] = pf[u];
    }
    const int found = cnt < K ? cnt : K;
    const int first = (found > 0) ? s_idx[wu][0] : 0;
    const int id    = (lane < found) ? s_idx[wu][lane] : first;
    s_idx[wu][lane] = id;                  // padded list (same-wave use only)

    // ---- Phase A2: channels 0,1 ----
    const size_t SK = (size_t)S * K;
    const float2 pxy = *(const float2*)&xb[(size_t)id * 2];
    float* ob = out + ((size_t)b * OC) * SK + (size_t)s * K;
    ob[lane]      = pxy.x - qx;
    ob[SK + lane] = pxy.y - qy;

    // ---- Phase A3: transpose slice (64 n x 32 c), block-cooperative ----
    {
        const int sid = bid;               // unswizzled slice mapping
        const int tb  = sid >> 9;          // batch
        const int nt  = (sid >> 1) & 255;
        const int chh = sid & 1;
        const int n0  = nt * 64;
        const int c0  = chh * 32;

        const int nl = t & 63, cs = t >> 6;     // cs = wave index 0..3
        float tv[8];
        #pragma unroll
        for (int j = 0; j < 8; ++j) {
            const int c = cs + j * 4;           // 0..31
            tv[j] = __builtin_nontemporal_load(&f[((size_t)tb * C + c0 + c) * N + n0 + nl]);
        }
        #pragma unroll
        for (int j = 0; j < 8; ++j) {
            const int c = cs + j * 4;
            smem[c * 65 + nl] = tv[j];          // banks l%32: 2-way, free
        }
        __syncthreads();
        const int cl = t & 31, nh = t >> 5;     // store coalesced over 32 c
        #pragma unroll
        for (int i = 0; i < 8; ++i) {
            const int nn = nh * 8 + i;
            ft[((size_t)tb * N + n0 + nn) * C + c0 + cl] = smem[cl * 65 + nn];
        }
    }

    // ---- all ft writes must be visible before any gather read ----
    cg::this_grid().sync();

    // ---- Phase B: gather (4 lanes/row) -> LDS stage -> 256B stores (R9) ----
    const int kk = lane >> 2;
    const int c2 = lane & 3;
    const float* __restrict__ ftb = ft + (size_t)b * N * C;
    float* owt = smem + wu * TP;

    int ids[4];
    #pragma unroll
    for (int g = 0; g < 4; ++g) ids[g] = s_idx[wu][g * 16 + kk];

    #pragma unroll
    for (int cc = 0; cc < 4; ++cc) {       // 16-channel chunks
        f32x4 v[4];
        #pragma unroll
        for (int g = 0; g < 4; ++g) {      // 16 rows x 64B line per instr
            v[g] = *(const f32x4*)&ftb[(size_t)ids[g] * C + cc * 16 + c2 * 4];
        }
        #pragma unroll
        for (int g = 0; g < 4; ++g) {
            const int pt = g * 16 + kk;
            *(f32x4*)&owt[pt * 17 + c2 * 4] = v[g];
        }
        #pragma unroll
        for (int c = 0; c < 16; ++c) {
            const float vv = owt[lane * 17 + c];
            ob[(size_t)(2 + cc * 16 + c) * SK + lane] = vv;
        }
    }
}

// ---------------------------------------------------------------------------
// Fallback path = R9 structure verbatim (two launches, no cooperative).
// ---------------------------------------------------------------------------
__global__ __launch_bounds__(256) void transpose_kernel(const float* __restrict__ f,
                                                        float* __restrict__ ft) {
    __shared__ float tile[64 * 65];
    const int n0 = blockIdx.x * 64;
    const int b  = blockIdx.y;
    const int t  = threadIdx.x;

    const int nl = t & 63, cl = t >> 6;
    #pragma unroll
    for (int cc = cl; cc < 64; cc += 4) {
        tile[cc * 65 + nl] = __builtin_nontemporal_load(&f[((size_t)b * C + cc) * N + n0 + nl]);
    }
    __syncthreads();

    const int cl2 = t & 63, nl2 = t >> 6;
    #pragma unroll
    for (int nn = nl2; nn < 64; nn += 4) {
        ft[((size_t)b * N + n0 + nn) * C + cl2] = tile[cl2 * 65 + nn];
    }
}

__global__ __launch_bounds__(256) void qag3_kernel(const float* __restrict__ xyz,
                                                   const float* __restrict__ new_xyz,
                                                   const float* __restrict__ ft,
                                                   const int* __restrict__ pointsnum,
                                                   float* __restrict__ out) {
    __shared__ int   s_idx[4][K];
    __shared__ float tile[4 * TP];

    const int t    = threadIdx.x;
    const int lane = t & 63;
    const int wu   = __builtin_amdgcn_readfirstlane(t >> 6);

    const int nwg = (B * S) / 4;
    const int bid = blockIdx.x;
    const int swz = (bid & (NXCD - 1)) * (nwg / NXCD) + (bid >> 3);

    const int q0 = swz * 4;
    const int b  = q0 >> 11;
    const int q  = q0 + wu;
    const int s  = (q0 & (S - 1)) + wu;

    const float qx = new_xyz[(size_t)q * 2 + 0];
    const float qy = new_xyz[(size_t)q * 2 + 1];
    const float* __restrict__ xb = xyz + (size_t)b * N * 2;

    int pn = pointsnum[b];
    pn = pn < 0 ? 0 : (pn > N ? N : pn);
    int cnt = 0;
    float2 p[4], pf[4];
    #pragma unroll
    for (int u = 0; u < 4; ++u) {
        const int i  = u * 64 + lane;
        const int ic = i < N ? i : N - 1;
        p[u] = *(const float2*)&xb[(size_t)ic * 2];
    }
    for (int base = 0; base < pn && cnt < K; base += 256) {
        #pragma unroll
        for (int u = 0; u < 4; ++u) {
            const int i  = base + 256 + u * 64 + lane;
            const int ic = i < N ? i : N - 1;
            pf[u] = *(const float2*)&xb[(size_t)ic * 2];
        }
        #pragma unroll
        for (int u = 0; u < 4; ++u) {
            const int i = base + u * 64 + lane;
            bool ok = false;
            if (i < pn) {
                const float dx = __fsub_rn(qx, p[u].x);
                const float dy = __fsub_rn(qy, p[u].y);
                const float d2 = __fadd_rn(__fmul_rn(dx, dx), __fmul_rn(dy, dy));
                ok = d2 < R2;
            }
            const unsigned long long m = __ballot(ok);
            if (ok) {
                const int pos = cnt + __popcll(m & ((1ull << lane) - 1ull));
                if (pos < K) s_idx[wu][pos] = i;
            }
            cnt += __popcll(m);
        }
        #pragma unroll
        for (int u = 0; u < 4; ++u) p[u] = pf[u];
    }
    const int found = cnt < K ? cnt : K;
    const int first = (found > 0) ? s_idx[wu][0] : 0;
    const int id    = (lane < found) ? s_idx[wu][lane] : first;
    s_idx[wu][lane] = id;

    const size_t SK = (size_t)S * K;
    const float2 pxy = *(const float2*)&xb[(size_t)id * 2];
    float* ob = out + ((size_t)b * OC) * SK + (size_t)s * K;
    ob[lane]      = pxy.x - qx;
    ob[SK + lane] = pxy.y - qy;

    const int kk = lane >> 2;
    const int c2 = lane & 3;
    const float* __restrict__ ftb = ft + (size_t)b * N * C;
    float* owt = tile + wu * TP;

    #pragma unroll
    for (int cc = 0; cc < 4; ++cc) {
        f32x4 v[4];
        #pragma unroll
        for (int g = 0; g < 4; ++g) {
            const int pt = g * 16 + kk;
            const int ip = s_idx[wu][pt];
            v[g] = *(const f32x4*)&ftb[(size_t)ip * C + cc * 16 + c2 * 4];
        }
        #pragma unroll
        for (int g = 0; g < 4; ++g) {
            const int pt = g * 16 + kk;
            *(f32x4*)&owt[pt * 17 + c2 * 4] = v[g];
        }
        #pragma unroll
        for (int c = 0; c < 16; ++c) {
            const float vv = owt[lane * 17 + c];
            ob[(size_t)(2 + cc * 16 + c) * SK + lane] = vv;
        }
    }
}

__global__ __launch_bounds__(256) void qag_fallback(const float* __restrict__ xyz,
                                                    const float* __restrict__ new_xyz,
                                                    const float* __restrict__ feat,
                                                    const int* __restrict__ pointsnum,
                                                    float* __restrict__ out) {
    __shared__ int s_idx[4][K];

    const int t    = threadIdx.x;
    const int lane = t & 63;
    const int wu   = __builtin_amdgcn_readfirstlane(t >> 6);
    const int q0   = blockIdx.x * 4;
    const int b    = q0 >> 11;
    const int q    = q0 + wu;
    const int s    = (q0 & (S - 1)) + wu;

    const float qx = new_xyz[(size_t)q * 2 + 0];
    const float qy = new_xyz[(size_t)q * 2 + 1];
    const float* __restrict__ xb = xyz + (size_t)b * N * 2;

    int pn = pointsnum[b];
    pn = pn < 0 ? 0 : (pn > N ? N : pn);
    int cnt = 0;
    for (int base = 0; base < pn && cnt < K; base += 256) {
        float2 p[4];
        #pragma unroll
        for (int u = 0; u < 4; ++u) {
            int i  = base + u * 64 + lane;
            int ic = i < N ? i : N - 1;
            p[u] = *(const float2*)&xb[(size_t)ic * 2];
        }
        #pragma unroll
        for (int u = 0; u < 4; ++u) {
            const int i = base + u * 64 + lane;
            bool ok = false;
            if (i < pn) {
                const float dx = __fsub_rn(qx, p[u].x);
                const float dy = __fsub_rn(qy, p[u].y);
                const float d2 = __fadd_rn(__fmul_rn(dx, dx), __fmul_rn(dy, dy));
                ok = d2 < R2;
            }
            const unsigned long long mm = __ballot(ok);
            if (ok) {
                const int pos = cnt + __popcll(mm & ((1ull << lane) - 1ull));
                if (pos < K) s_idx[wu][pos] = i;
            }
            cnt += __popcll(mm);
        }
    }
    const int found = cnt < K ? cnt : K;
    const int first = (found > 0) ? s_idx[wu][0] : 0;
    const int id    = (lane < found) ? s_idx[wu][lane] : first;

    const size_t SK = (size_t)S * K;
    const float2 pxy = *(const float2*)&xb[(size_t)id * 2];
    float* ob = out + ((size_t)b * OC) * SK + (size_t)s * K;
    ob[lane]      = pxy.x - qx;
    ob[SK + lane] = pxy.y - qy;

    const float* __restrict__ fb = feat + (size_t)b * C * N;
    for (int c = 0; c < C; ++c) {
        ob[(size_t)(2 + c) * SK + lane] = fb[(size_t)c * N + id];
    }
}

extern "C" void kernel_launch(void* const* d_in, const int* in_sizes, int n_in,
                              void* d_out, int out_size, void* d_ws, size_t ws_size,
                              hipStream_t stream) {
    const float* xyz       = (const float*)d_in[0];
    const float* new_xyz   = (const float*)d_in[1];
    const float* feat      = (const float*)d_in[2];
    const int*   pointsnum = (const int*)d_in[3];
    float*       out       = (float*)d_out;

    const size_t ft_bytes = (size_t)B * N * C * sizeof(float);    // 16.8 MB
    if (ws_size >= ft_bytes) {
        float* ft = (float*)d_ws;
        void* args[6];
        args[0] = (void*)&feat; args[1] = (void*)&xyz; args[2] = (void*)&new_xyz;
        args[3] = (void*)&pointsnum; args[4] = (void*)&ft; args[5] = (void*)&out;
        hipError_t e = hipLaunchCooperativeKernel((const void*)coop_kernel,
                                                  dim3(B * S / 4), dim3(256),
                                                  args, 0, stream);
        if (e != hipSuccess) {
            // same output via the non-cooperative R9 path
            transpose_kernel<<<dim3(N / 64, B), 256, 0, stream>>>(feat, ft);
            qag3_kernel<<<B * S / 4, 256, 0, stream>>>(xyz, new_xyz, ft, pointsnum, out);
        }
    } else {
        qag_fallback<<<B * S / 4, 256, 0, stream>>>(xyz, new_xyz, feat, pointsnum, out);
    }
}

// Round 13
// 53.331 us; speedup vs baseline: 6.1393x; 6.1393x over previous
//
#include <hip/hip_runtime.h>
#include <stdint.h>

#define B 4
#define N 16384
#define S 2048
#define C 64
#define K 64
#define OC 66
#define R2 0.01f
#define NXCD 8
#define TP 1089   // per-wave gather staging: 64 points x pitch 17 (+skew)

typedef float f32x4 __attribute__((ext_vector_type(4)));

// ---------------------------------------------------------------------------
// Kernel 1 (prep, heterogeneous grid):
//   blocks [0, 1024):    transpose features (B,C,N) -> ft (B,N,C)
//   blocks [1024, 3072): ball-query scan (one wave/query, R9-verbatim)
//                        -> idx[B*S][K] + output channels 0,1
// Scan compute overlaps the transpose's HBM streaming.
// ---------------------------------------------------------------------------
__global__ __launch_bounds__(256) void prep_kernel(const float* __restrict__ f,
                                                   const float* __restrict__ xyz,
                                                   const float* __restrict__ new_xyz,
                                                   const int* __restrict__ pointsnum,
                                                   float* __restrict__ ft,
                                                   int* __restrict__ idx,
                                                   float* __restrict__ out) {
    __shared__ float tile[64 * 65];
    __shared__ int   s_idx[4][K];

    const int t = threadIdx.x;

    if (blockIdx.x < 1024) {
        // ---------------- transpose path (R9 verbatim) ----------------
        const int n0 = (blockIdx.x & 255) * 64;
        const int b  = blockIdx.x >> 8;

        const int nl = t & 63, cl = t >> 6;
        #pragma unroll
        for (int cc = cl; cc < 64; cc += 4) {
            tile[cc * 65 + nl] = __builtin_nontemporal_load(&f[((size_t)b * C + cc) * N + n0 + nl]);
        }
        __syncthreads();

        const int cl2 = t & 63, nl2 = t >> 6;
        #pragma unroll
        for (int nn = nl2; nn < 64; nn += 4) {
            ft[((size_t)b * N + n0 + nn) * C + cl2] = tile[cl2 * 65 + nn];
        }
        return;
    }

    // ---------------- scan path (one wave per query, R9 verbatim) ----------
    const int lane = t & 63;
    const int wu   = __builtin_amdgcn_readfirstlane(t >> 6);
    const int q0   = (int)(blockIdx.x - 1024) * 4;
    const int b    = q0 >> 11;             // / S (S=2048)
    const int q    = q0 + wu;
    const int s    = (q0 & (S - 1)) + wu;

    const float qx = new_xyz[(size_t)q * 2 + 0];
    const float qy = new_xyz[(size_t)q * 2 + 1];
    const float* __restrict__ xb = xyz + (size_t)b * N * 2;

    int pn = pointsnum[b];
    pn = pn < 0 ? 0 : (pn > N ? N : pn);
    int cnt = 0;
    float2 p[4], pf[4];
    #pragma unroll
    for (int u = 0; u < 4; ++u) {
        const int i  = u * 64 + lane;
        const int ic = i < N ? i : N - 1;
        p[u] = *(const float2*)&xb[(size_t)ic * 2];
    }
    for (int base = 0; base < pn && cnt < K; base += 256) {
        #pragma unroll
        for (int u = 0; u < 4; ++u) {       // prefetch next super-chunk
            const int i  = base + 256 + u * 64 + lane;
            const int ic = i < N ? i : N - 1;
            pf[u] = *(const float2*)&xb[(size_t)ic * 2];
        }
        #pragma unroll
        for (int u = 0; u < 4; ++u) {
            const int i = base + u * 64 + lane;
            bool ok = false;
            if (i < pn) {
                // match numpy f32 rounding exactly: no FMA contraction
                const float dx = __fsub_rn(qx, p[u].x);
                const float dy = __fsub_rn(qy, p[u].y);
                const float d2 = __fadd_rn(__fmul_rn(dx, dx), __fmul_rn(dy, dy));
                ok = d2 < R2;
            }
            const unsigned long long m = __ballot(ok);
            if (ok) {
                const int pos = cnt + __popcll(m & ((1ull << lane) - 1ull));
                if (pos < K) s_idx[wu][pos] = i;
            }
            cnt += __popcll(m);
        }
        #pragma unroll
        for (int u = 0; u < 4; ++u) p[u] = pf[u];
    }
    const int found = cnt < K ? cnt : K;
    const int first = (found > 0) ? s_idx[wu][0] : 0;   // pad value (0 if none)
    const int id    = (lane < found) ? s_idx[wu][lane] : first;

    idx[(size_t)q * K + lane] = id;                     // coalesced 256B

    // channels 0,1: grouped_xyz = xyz[id] - new_xyz[s]
    const size_t SK = (size_t)S * K;
    const float2 pxy = *(const float2*)&xb[(size_t)id * 2];
    float* ob = out + ((size_t)b * OC) * SK + (size_t)s * K;
    ob[lane]      = pxy.x - qx;
    ob[SK + lane] = pxy.y - qy;
}

// ---------------------------------------------------------------------------
// Kernel 2 (gather): R9 phase-2 VERBATIM (4-lanes/row gather, wave-private
// pitch-17 LDS staging, 64x256B cached stores, zero barriers, XCD swizzle);
// ids come from ws instead of an in-kernel scan.
// ---------------------------------------------------------------------------
__global__ __launch_bounds__(256) void gather3_kernel(const float* __restrict__ ft,
                                                      const int* __restrict__ idx,
                                                      float* __restrict__ out) {
    __shared__ float tile[4 * TP];

    const int t    = threadIdx.x;
    const int lane = t & 63;
    const int wu   = __builtin_amdgcn_readfirstlane(t >> 6);

    // bijective XCD swizzle: nwg = 2048, 2048 % 8 == 0
    const int nwg = (B * S) / 4;
    const int bid = blockIdx.x;
    const int swz = (bid & (NXCD - 1)) * (nwg / NXCD) + (bid >> 3);

    const int q0 = swz * 4;
    const int b  = q0 >> 11;
    const int q  = q0 + wu;
    const int s  = (q0 & (S - 1)) + wu;

    const int kk = lane >> 2;              // point sub-index 0..15
    const int c2 = lane & 3;               // float4 slot within 16-ch chunk

    int ids[4];
    #pragma unroll
    for (int g = 0; g < 4; ++g) {
        ids[g] = idx[(size_t)q * K + g * 16 + kk];
    }

    const size_t SK = (size_t)S * K;
    float* ob = out + ((size_t)b * OC) * SK + (size_t)s * K;
    const float* __restrict__ ftb = ft + (size_t)b * N * C;
    float* owt = tile + wu * TP;

    #pragma unroll
    for (int cc = 0; cc < 4; ++cc) {       // 16-channel chunks
        f32x4 v[4];
        #pragma unroll
        for (int g = 0; g < 4; ++g) {      // 16 rows x full 64B line per instr
            v[g] = *(const f32x4*)&ftb[(size_t)ids[g] * C + cc * 16 + c2 * 4];
        }
        #pragma unroll
        for (int g = 0; g < 4; ++g) {
            const int pt = g * 16 + kk;
            *(f32x4*)&owt[pt * 17 + c2 * 4] = v[g];     // b128, skewed banks
        }
        #pragma unroll
        for (int c = 0; c < 16; ++c) {
            const float vv = owt[lane * 17 + c];
            ob[(size_t)(2 + cc * 16 + c) * SK + lane] = vv;
        }
    }
}

// ---------------------------------------------------------------------------
// Fallback (tiny ws): fused kernel gathering directly from (B,C,N) feat.
// ---------------------------------------------------------------------------
__global__ __launch_bounds__(256) void qag_fallback(const float* __restrict__ xyz,
                                                    const float* __restrict__ new_xyz,
                                                    const float* __restrict__ feat,
                                                    const int* __restrict__ pointsnum,
                                                    float* __restrict__ out) {
    __shared__ int s_idx[4][K];

    const int t    = threadIdx.x;
    const int lane = t & 63;
    const int wu   = __builtin_amdgcn_readfirstlane(t >> 6);
    const int q0   = blockIdx.x * 4;
    const int b    = q0 >> 11;
    const int q    = q0 + wu;
    const int s    = (q0 & (S - 1)) + wu;

    const float qx = new_xyz[(size_t)q * 2 + 0];
    const float qy = new_xyz[(size_t)q * 2 + 1];
    const float* __restrict__ xb = xyz + (size_t)b * N * 2;

    int pn = pointsnum[b];
    pn = pn < 0 ? 0 : (pn > N ? N : pn);
    int cnt = 0;
    for (int base = 0; base < pn && cnt < K; base += 256) {
        float2 p[4];
        #pragma unroll
        for (int u = 0; u < 4; ++u) {
            int i  = base + u * 64 + lane;
            int ic = i < N ? i : N - 1;
            p[u] = *(const float2*)&xb[(size_t)ic * 2];
        }
        #pragma unroll
        for (int u = 0; u < 4; ++u) {
            const int i = base + u * 64 + lane;
            bool ok = false;
            if (i < pn) {
                const float dx = __fsub_rn(qx, p[u].x);
                const float dy = __fsub_rn(qy, p[u].y);
                const float d2 = __fadd_rn(__fmul_rn(dx, dx), __fmul_rn(dy, dy));
                ok = d2 < R2;
            }
            const unsigned long long mm = __ballot(ok);
            if (ok) {
                const int pos = cnt + __popcll(mm & ((1ull << lane) - 1ull));
                if (pos < K) s_idx[wu][pos] = i;
            }
            cnt += __popcll(mm);
        }
    }
    const int found = cnt < K ? cnt : K;
    const int first = (found > 0) ? s_idx[wu][0] : 0;
    const int id    = (lane < found) ? s_idx[wu][lane] : first;

    const size_t SK = (size_t)S * K;
    const float2 pxy = *(const float2*)&xb[(size_t)id * 2];
    float* ob = out + ((size_t)b * OC) * SK + (size_t)s * K;
    ob[lane]      = pxy.x - qx;
    ob[SK + lane] = pxy.y - qy;

    const float* __restrict__ fb = feat + (size_t)b * C * N;
    for (int c = 0; c < C; ++c) {
        ob[(size_t)(2 + c) * SK + lane] = fb[(size_t)c * N + id];
    }
}

extern "C" void kernel_launch(void* const* d_in, const int* in_sizes, int n_in,
                              void* d_out, int out_size, void* d_ws, size_t ws_size,
                              hipStream_t stream) {
    const float* xyz       = (const float*)d_in[0];
    const float* new_xyz   = (const float*)d_in[1];
    const float* feat      = (const float*)d_in[2];
    const int*   pointsnum = (const int*)d_in[3];
    float*       out       = (float*)d_out;

    const size_t ft_bytes  = (size_t)B * N * C * sizeof(float);   // 16.8 MB
    const size_t idx_bytes = (size_t)B * S * K * sizeof(int);     //  2.1 MB

    if (ws_size >= ft_bytes + idx_bytes) {
        float* ft  = (float*)d_ws;
        int*   idx = (int*)((char*)d_ws + ft_bytes);
        prep_kernel<<<1024 + B * S / 4, 256, 0, stream>>>(feat, xyz, new_xyz, pointsnum, ft, idx, out);
        gather3_kernel<<<B * S / 4, 256, 0, stream>>>(ft, idx, out);
    } else {
        qag_fallback<<<B * S / 4, 256, 0, stream>>>(xyz, new_xyz, feat, pointsnum, out);
    }
}

// Round 14
// 48.796 us; speedup vs baseline: 6.7099x; 1.0929x over previous
//
#include <hip/hip_runtime.h>
#include <stdint.h>

#define B 4
#define N 16384
#define S 2048
#define C 64
#define K 64
#define OC 66
#define R2 0.01f
#define NXCD 8
#define TP 1089   // per-wave tile: 64 points x pitch 17 floats (+skew)

typedef float f32x4 __attribute__((ext_vector_type(4)));

// ---------------------------------------------------------------------------
// Kernel 1: transpose features (B,C,N) -> ft (B,N,C).
// ---------------------------------------------------------------------------
__global__ __launch_bounds__(256) void transpose_kernel(const float* __restrict__ f,
                                                        float* __restrict__ ft) {
    __shared__ float tile[64 * 65];
    const int n0 = blockIdx.x * 64;
    const int b  = blockIdx.y;
    const int t  = threadIdx.x;

    const int nl = t & 63, cl = t >> 6;
    #pragma unroll
    for (int cc = cl; cc < 64; cc += 4) {
        tile[cc * 65 + nl] = __builtin_nontemporal_load(&f[((size_t)b * C + cc) * N + n0 + nl]);
    }
    __syncthreads();

    const int cl2 = t & 63, nl2 = t >> 6;
    #pragma unroll
    for (int nn = nl2; nn < 64; nn += 4) {
        ft[((size_t)b * N + n0 + nn) * C + cl2] = tile[cl2 * 65 + nn];
    }
}

// ---------------------------------------------------------------------------
// Kernel 2: fused ball-query + group + concat. ZERO BARRIERS.
// Each wave owns one query end-to-end; LDS regions are wave-private, so no
// __syncthreads -> no s_waitcnt vmcnt(0) drains -> stores stay in flight
// continuously. Scan prefetches the next super-chunk so loads aren't
// serialized behind the cnt<K exit branch. Cached (non-NT) stores; XCD
// swizzle for ft L2 locality; 4-lanes-per-row gather (full 64B lines);
// wave-private pitch-17 LDS staging; 64x256B store runs.
// This configuration is the measured minimum (48.5 us); six subsequent
// structural variants (splits, direct stores, grid-sync fusion) all lost.
// ---------------------------------------------------------------------------
__global__ __launch_bounds__(256) void qag3_kernel(const float* __restrict__ xyz,
                                                   const float* __restrict__ new_xyz,
                                                   const float* __restrict__ ft,
                                                   const int* __restrict__ pointsnum,
                                                   float* __restrict__ out) {
    __shared__ int   s_idx[4][K];          // per-wave index list
    __shared__ float tile[4 * TP];         // per-wave private staging

    const int t    = threadIdx.x;
    const int lane = t & 63;
    const int wu   = __builtin_amdgcn_readfirstlane(t >> 6);

    // bijective XCD swizzle: nwg = 2048, 2048 % 8 == 0
    const int nwg = (B * S) / 4;
    const int bid = blockIdx.x;
    const int swz = (bid & (NXCD - 1)) * (nwg / NXCD) + (bid >> 3);

    const int q0 = swz * 4;
    const int b  = q0 >> 11;               // / S
    const int q  = q0 + wu;
    const int s  = (q0 & (S - 1)) + wu;

    const float qx = new_xyz[(size_t)q * 2 + 0];
    const float qy = new_xyz[(size_t)q * 2 + 1];
    const float* __restrict__ xb = xyz + (size_t)b * N * 2;

    // ---- Phase 1: ordered ball-query scan, next-chunk prefetch ----
    int pn = pointsnum[b];
    pn = pn < 0 ? 0 : (pn > N ? N : pn);
    int cnt = 0;
    float2 p[4], pf[4];
    #pragma unroll
    for (int u = 0; u < 4; ++u) {
        const int i  = u * 64 + lane;
        const int ic = i < N ? i : N - 1;
        p[u] = *(const float2*)&xb[(size_t)ic * 2];
    }
    for (int base = 0; base < pn && cnt < K; base += 256) {
        #pragma unroll
        for (int u = 0; u < 4; ++u) {       // prefetch next super-chunk
            const int i  = base + 256 + u * 64 + lane;
            const int ic = i < N ? i : N - 1;
            pf[u] = *(const float2*)&xb[(size_t)ic * 2];
        }
        #pragma unroll
        for (int u = 0; u < 4; ++u) {
            const int i = base + u * 64 + lane;
            bool ok = false;
            if (i < pn) {
                // match numpy f32 rounding exactly: no FMA contraction
                const float dx = __fsub_rn(qx, p[u].x);
                const float dy = __fsub_rn(qy, p[u].y);
                const float d2 = __fadd_rn(__fmul_rn(dx, dx), __fmul_rn(dy, dy));
                ok = d2 < R2;
            }
            const unsigned long long m = __ballot(ok);
            if (ok) {
                const int pos = cnt + __popcll(m & ((1ull << lane) - 1ull));
                if (pos < K) s_idx[wu][pos] = i;
            }
            cnt += __popcll(m);
        }
        #pragma unroll
        for (int u = 0; u < 4; ++u) p[u] = pf[u];
    }
    const int found = cnt < K ? cnt : K;
    const int first = (found > 0) ? s_idx[wu][0] : 0;
    const int id    = (lane < found) ? s_idx[wu][lane] : first;
    s_idx[wu][lane] = id;                  // padded list (same-wave use only)

    // ---- channels 0,1: grouped_xyz = xyz[id] - new_xyz[s] ----
    const size_t SK = (size_t)S * K;
    const float2 pxy = *(const float2*)&xb[(size_t)id * 2];
    float* ob = out + ((size_t)b * OC) * SK + (size_t)s * K;   // own query
    ob[lane]      = pxy.x - qx;
    ob[SK + lane] = pxy.y - qy;

    // ---- Phase 2: per-wave gather -> private LDS -> 256B cached stores ----
    const int kk = lane >> 2;              // point-sub 0..15
    const int c2 = lane & 3;               // float4 slot in 16-ch chunk
    const float* __restrict__ ftb = ft + (size_t)b * N * C;
    float* owt = tile + wu * TP;

    #pragma unroll
    for (int cc = 0; cc < 4; ++cc) {       // 16-channel chunks
        f32x4 v[4];
        #pragma unroll
        for (int g = 0; g < 4; ++g) {      // own query's 64 points, 16 rows/instr
            const int pt = g * 16 + kk;
            const int ip = s_idx[wu][pt];
            v[g] = *(const f32x4*)&ftb[(size_t)ip * C + cc * 16 + c2 * 4];
        }
        #pragma unroll
        for (int g = 0; g < 4; ++g) {
            const int pt = g * 16 + kk;
            *(f32x4*)&owt[pt * 17 + c2 * 4] = v[g];     // b128, skewed banks
        }
        // lane = k; 16 channels: ds_read stride 17 (2-way, free) + 256B store
        #pragma unroll
        for (int c = 0; c < 16; ++c) {
            const float vv = owt[lane * 17 + c];
            ob[(size_t)(2 + cc * 16 + c) * SK + lane] = vv;
        }
    }
}

// ---------------------------------------------------------------------------
// Fallback (tiny ws): fused kernel gathering directly from (B,C,N) feat.
// ---------------------------------------------------------------------------
__global__ __launch_bounds__(256) void qag_fallback(const float* __restrict__ xyz,
                                                    const float* __restrict__ new_xyz,
                                                    const float* __restrict__ feat,
                                                    const int* __restrict__ pointsnum,
                                                    float* __restrict__ out) {
    __shared__ int s_idx[4][K];

    const int t    = threadIdx.x;
    const int lane = t & 63;
    const int wu   = __builtin_amdgcn_readfirstlane(t >> 6);
    const int q0   = blockIdx.x * 4;
    const int b    = q0 >> 11;
    const int q    = q0 + wu;
    const int s    = (q0 & (S - 1)) + wu;

    const float qx = new_xyz[(size_t)q * 2 + 0];
    const float qy = new_xyz[(size_t)q * 2 + 1];
    const float* __restrict__ xb = xyz + (size_t)b * N * 2;

    int pn = pointsnum[b];
    pn = pn < 0 ? 0 : (pn > N ? N : pn);
    int cnt = 0;
    for (int base = 0; base < pn && cnt < K; base += 256) {
        float2 p[4];
        #pragma unroll
        for (int u = 0; u < 4; ++u) {
            int i  = base + u * 64 + lane;
            int ic = i < N ? i : N - 1;
            p[u] = *(const float2*)&xb[(size_t)ic * 2];
        }
        #pragma unroll
        for (int u = 0; u < 4; ++u) {
            const int i = base + u * 64 + lane;
            bool ok = false;
            if (i < pn) {
                const float dx = __fsub_rn(qx, p[u].x);
                const float dy = __fsub_rn(qy, p[u].y);
                const float d2 = __fadd_rn(__fmul_rn(dx, dx), __fmul_rn(dy, dy));
                ok = d2 < R2;
            }
            const unsigned long long mm = __ballot(ok);
            if (ok) {
                const int pos = cnt + __popcll(mm & ((1ull << lane) - 1ull));
                if (pos < K) s_idx[wu][pos] = i;
            }
            cnt += __popcll(mm);
        }
    }
    const int found = cnt < K ? cnt : K;
    const int first = (found > 0) ? s_idx[wu][0] : 0;
    const int id    = (lane < found) ? s_idx[wu][lane] : first;

    const size_t SK = (size_t)S * K;
    const float2 pxy = *(const float2*)&xb[(size_t)id * 2];
    float* ob = out + ((size_t)b * OC) * SK + (size_t)s * K;
    ob[lane]      = pxy.x - qx;
    ob[SK + lane] = pxy.y - qy;

    const float* __restrict__ fb = feat + (size_t)b * C * N;
    for (int c = 0; c < C; ++c) {
        ob[(size_t)(2 + c) * SK + lane] = fb[(size_t)c * N + id];
    }
}

extern "C" void kernel_launch(void* const* d_in, const int* in_sizes, int n_in,
                              void* d_out, int out_size, void* d_ws, size_t ws_size,
                              hipStream_t stream) {
    const float* xyz       = (const float*)d_in[0];
    const float* new_xyz   = (const float*)d_in[1];
    const float* feat      = (const float*)d_in[2];
    const int*   pointsnum = (const int*)d_in[3];
    float*       out       = (float*)d_out;

    const size_t ft_bytes = (size_t)B * N * C * sizeof(float);    // 16.8 MB
    if (ws_size >= ft_bytes) {
        float* ft = (float*)d_ws;
        transpose_kernel<<<dim3(N / 64, B), 256, 0, stream>>>(feat, ft);
        qag3_kernel<<<B * S / 4, 256, 0, stream>>>(xyz, new_xyz, ft, pointsnum, out);
    } else {
        qag_fallback<<<B * S / 4, 256, 0, stream>>>(xyz, new_xyz, feat, pointsnum, out);
    }
}